// Round 1
// baseline (2220.412 us; speedup 1.0000x reference)
//
#include <hip/hip_runtime.h>
#include <hip/hip_bf16.h>

#define D_MODEL 4096
#define D_FF    11008
#define NTOK    4096   // 2*2048 tokens

typedef __attribute__((ext_vector_type(8))) short short8;
typedef __attribute__((ext_vector_type(4))) float f32x4;

// ---------------- fp32 -> bf16 convert (8 elems/thread) ----------------
__global__ void k_cvt(const float* __restrict__ in, __hip_bfloat16* __restrict__ out, int n8) {
    int i = blockIdx.x * blockDim.x + threadIdx.x;
    if (i >= n8) return;
    const float4* p = (const float4*)in;
    float4 v0 = p[(size_t)i * 2];
    float4 v1 = p[(size_t)i * 2 + 1];
    float vals[8] = {v0.x, v0.y, v0.z, v0.w, v1.x, v1.y, v1.z, v1.w};
    short8 o;
#pragma unroll
    for (int j = 0; j < 8; ++j) {
        __hip_bfloat16 b = __float2bfloat16(vals[j]);
        o[j] = *reinterpret_cast<short*>(&b);
    }
    *reinterpret_cast<short8*>(out + (size_t)i * 8) = o;
}

// ------------- async stage of a 128x64 bf16 tile into LDS --------------
// 16384 bytes = 4 issues * 4 waves * 64 lanes * 16B
// LDS dest is wave-uniform base + lane*16 (HW rule); global src is per-lane.
static __device__ __forceinline__ void stage_tile(
    const __hip_bfloat16* gbase, int ld, __hip_bfloat16* lds, int lane, int wave)
{
#pragma unroll
    for (int ii = 0; ii < 4; ++ii) {
        int elem = ii * 2048 + wave * 512;          // wave-uniform element offset
        int le   = elem + lane * 8;
        int r = le >> 6, c = le & 63;
        const __hip_bfloat16* g = gbase + (long)r * ld + c;
        __builtin_amdgcn_global_load_lds(
            (const __attribute__((address_space(1))) void*)g,
            (__attribute__((address_space(3))) void*)(lds + elem),
            16, 0, 0);
    }
}

// ---------------- stage 1: h = silu(x Wg^T) * (x Wu^T) -----------------
// A = X [NTOK][D_MODEL] bf16, B = W [D_FF][D_MODEL] bf16 (B^T layout, K-contig)
__global__ __launch_bounds__(256)
void k_gateup(const __hip_bfloat16* __restrict__ X,
              const __hip_bfloat16* __restrict__ Wg,
              const __hip_bfloat16* __restrict__ Wu,
              __hip_bfloat16* __restrict__ H)
{
    __shared__ __hip_bfloat16 sA[128 * 64];
    __shared__ __hip_bfloat16 sG[128 * 64];
    __shared__ __hip_bfloat16 sU[128 * 64];

    const int tid  = threadIdx.x;
    const int lane = tid & 63;
    const int wave = tid >> 6;
    const int wm = wave >> 1, wn = wave & 1;
    const int m0 = blockIdx.y * 128;
    const int n0 = blockIdx.x * 128;
    const int r16 = lane & 15;
    const int g4  = lane >> 4;

    f32x4 accg[4][4], accu[4][4];
#pragma unroll
    for (int i = 0; i < 4; ++i)
#pragma unroll
        for (int j = 0; j < 4; ++j) {
            accg[i][j] = (f32x4){0.f, 0.f, 0.f, 0.f};
            accu[i][j] = (f32x4){0.f, 0.f, 0.f, 0.f};
        }

    const int nK = D_MODEL / 64;
    for (int t = 0; t < nK; ++t) {
        const int k0 = t * 64;
        stage_tile(X  + (long)m0 * D_MODEL + k0, D_MODEL, sA, lane, wave);
        stage_tile(Wg + (long)n0 * D_MODEL + k0, D_MODEL, sG, lane, wave);
        stage_tile(Wu + (long)n0 * D_MODEL + k0, D_MODEL, sU, lane, wave);
        __syncthreads();
#pragma unroll
        for (int kk = 0; kk < 2; ++kk) {
            const int kb = kk * 32 + g4 * 8;
            short8 a[4], bg[4], bu[4];
#pragma unroll
            for (int i = 0; i < 4; ++i)
                a[i] = *reinterpret_cast<const short8*>(&sA[(wm * 64 + i * 16 + r16) * 64 + kb]);
#pragma unroll
            for (int j = 0; j < 4; ++j) {
                bg[j] = *reinterpret_cast<const short8*>(&sG[(wn * 64 + j * 16 + r16) * 64 + kb]);
                bu[j] = *reinterpret_cast<const short8*>(&sU[(wn * 64 + j * 16 + r16) * 64 + kb]);
            }
#pragma unroll
            for (int i = 0; i < 4; ++i)
#pragma unroll
                for (int j = 0; j < 4; ++j) {
                    accg[i][j] = __builtin_amdgcn_mfma_f32_16x16x32_bf16(a[i], bg[j], accg[i][j], 0, 0, 0);
                    accu[i][j] = __builtin_amdgcn_mfma_f32_16x16x32_bf16(a[i], bu[j], accu[i][j], 0, 0, 0);
                }
        }
        __syncthreads();
    }

    // epilogue: h = silu(g) * u, bf16 store
#pragma unroll
    for (int i = 0; i < 4; ++i)
#pragma unroll
        for (int j = 0; j < 4; ++j)
#pragma unroll
            for (int r = 0; r < 4; ++r) {
                int row = m0 + wm * 64 + i * 16 + g4 * 4 + r;
                int col = n0 + wn * 64 + j * 16 + r16;
                float g = accg[i][j][r];
                float u = accu[i][j][r];
                float s = g / (1.f + __expf(-g));
                H[(long)row * D_FF + col] = __float2bfloat16(s * u);
            }
}

// ---------------- stage 2: y = h Wd^T  (f32 output) --------------------
// A = H [NTOK][D_FF] bf16, B = Wd [D_MODEL][D_FF] bf16 (B^T layout, K-contig)
__global__ __launch_bounds__(256)
void k_down(const __hip_bfloat16* __restrict__ H,
            const __hip_bfloat16* __restrict__ Wd,
            float* __restrict__ Y)
{
    __shared__ __hip_bfloat16 sA[128 * 64];
    __shared__ __hip_bfloat16 sB[128 * 64];

    const int tid  = threadIdx.x;
    const int lane = tid & 63;
    const int wave = tid >> 6;
    const int wm = wave >> 1, wn = wave & 1;
    const int m0 = blockIdx.y * 128;
    const int n0 = blockIdx.x * 128;
    const int r16 = lane & 15;
    const int g4  = lane >> 4;

    f32x4 acc[4][4];
#pragma unroll
    for (int i = 0; i < 4; ++i)
#pragma unroll
        for (int j = 0; j < 4; ++j)
            acc[i][j] = (f32x4){0.f, 0.f, 0.f, 0.f};

    const int nK = D_FF / 64;   // 172
    for (int t = 0; t < nK; ++t) {
        const int k0 = t * 64;
        stage_tile(H  + (long)m0 * D_FF + k0, D_FF, sA, lane, wave);
        stage_tile(Wd + (long)n0 * D_FF + k0, D_FF, sB, lane, wave);
        __syncthreads();
#pragma unroll
        for (int kk = 0; kk < 2; ++kk) {
            const int kb = kk * 32 + g4 * 8;
            short8 a[4], b[4];
#pragma unroll
            for (int i = 0; i < 4; ++i)
                a[i] = *reinterpret_cast<const short8*>(&sA[(wm * 64 + i * 16 + r16) * 64 + kb]);
#pragma unroll
            for (int j = 0; j < 4; ++j)
                b[j] = *reinterpret_cast<const short8*>(&sB[(wn * 64 + j * 16 + r16) * 64 + kb]);
#pragma unroll
            for (int i = 0; i < 4; ++i)
#pragma unroll
                for (int j = 0; j < 4; ++j)
                    acc[i][j] = __builtin_amdgcn_mfma_f32_16x16x32_bf16(a[i], b[j], acc[i][j], 0, 0, 0);
        }
        __syncthreads();
    }

#pragma unroll
    for (int i = 0; i < 4; ++i)
#pragma unroll
        for (int j = 0; j < 4; ++j)
#pragma unroll
            for (int r = 0; r < 4; ++r) {
                int row = m0 + wm * 64 + i * 16 + g4 * 4 + r;
                int col = n0 + wn * 64 + j * 16 + r16;
                Y[(long)row * D_MODEL + col] = acc[i][j][r];
            }
}

extern "C" void kernel_launch(void* const* d_in, const int* in_sizes, int n_in,
                              void* d_out, int out_size, void* d_ws, size_t ws_size,
                              hipStream_t stream) {
    const float* x  = (const float*)d_in[0];
    const float* wg = (const float*)d_in[1];
    const float* wu = (const float*)d_in[2];
    const float* wd = (const float*)d_in[3];
    float* y = (float*)d_out;

    char* ws = (char*)d_ws;
    const size_t szX  = (size_t)NTOK * D_MODEL * 2;
    const size_t szW  = (size_t)D_FF * D_MODEL * 2;
    const size_t szH  = (size_t)NTOK * D_FF * 2;
    __hip_bfloat16* Xb  = (__hip_bfloat16*)(ws);
    __hip_bfloat16* Wgb = (__hip_bfloat16*)(ws + szX);
    __hip_bfloat16* Wub = (__hip_bfloat16*)(ws + szX + szW);
    __hip_bfloat16* Wdb = (__hip_bfloat16*)(ws + szX + 2 * szW);
    __hip_bfloat16* Hb  = (__hip_bfloat16*)(ws + szX + 3 * szW);
    (void)szH; (void)ws_size; (void)out_size; (void)n_in; (void)in_sizes;

    const int nX = NTOK * D_MODEL / 8;
    const int nW = D_FF * D_MODEL / 8;
    k_cvt<<<(nX + 255) / 256, 256, 0, stream>>>(x, Xb, nX);
    k_cvt<<<(nW + 255) / 256, 256, 0, stream>>>(wg, Wgb, nW);
    k_cvt<<<(nW + 255) / 256, 256, 0, stream>>>(wu, Wub, nW);
    k_cvt<<<(nW + 255) / 256, 256, 0, stream>>>(wd, Wdb, nW);

    k_gateup<<<dim3(D_FF / 128, NTOK / 128), 256, 0, stream>>>(Xb, Wgb, Wub, Hb);
    k_down<<<dim3(D_MODEL / 128, NTOK / 128), 256, 0, stream>>>(Hb, Wdb, y);
}

// Round 2
// 2219.752 us; speedup vs baseline: 1.0003x; 1.0003x over previous
//
#include <hip/hip_runtime.h>
#include <hip/hip_bf16.h>

#define D_MODEL 4096
#define D_FF    11008
#define NTOK    4096   // 2*2048 tokens

typedef __attribute__((ext_vector_type(8))) short short8;
typedef __attribute__((ext_vector_type(4))) float f32x4;

// ---------------- fp32 -> bf16 convert (8 elems/thread) ----------------
__global__ void k_cvt(const float* __restrict__ in, __hip_bfloat16* __restrict__ out, int n8) {
    int i = blockIdx.x * blockDim.x + threadIdx.x;
    if (i >= n8) return;
    const float4* p = (const float4*)in;
    float4 v0 = p[(size_t)i * 2];
    float4 v1 = p[(size_t)i * 2 + 1];
    float vals[8] = {v0.x, v0.y, v0.z, v0.w, v1.x, v1.y, v1.z, v1.w};
    short8 o;
#pragma unroll
    for (int j = 0; j < 8; ++j) {
        __hip_bfloat16 b = __float2bfloat16(vals[j]);
        o[j] = *reinterpret_cast<short*>(&b);
    }
    *reinterpret_cast<short8*>(out + (size_t)i * 8) = o;
}

// ------------- async stage of a 128x64 bf16 tile into LDS --------------
// LDS dest must be linear (wave-uniform base + lane*16 per HW). To get a
// bank-conflict-free READ layout we pre-permute the GLOBAL source chunk:
// physical chunk p within row r holds logical chunk c = p ^ (r&7).
// (rule #21: swizzle both sides — source permutation == read permutation)
static __device__ __forceinline__ void stage_tile_sw(
    const __hip_bfloat16* gbase, int ld, __hip_bfloat16* lds, int lane, int wave)
{
#pragma unroll
    for (int ii = 0; ii < 4; ++ii) {
        int elem = ii * 2048 + wave * 512;          // wave-uniform element offset
        int le   = elem + lane * 8;                 // this lane's linear dest
        int r = le >> 6;                            // row (0..127), 64 elems/row
        int p = (le >> 3) & 7;                      // physical 16B chunk in row
        int c = p ^ (r & 7);                        // logical chunk to fetch
        const __hip_bfloat16* g = gbase + (long)r * ld + c * 8;
        __builtin_amdgcn_global_load_lds(
            (const __attribute__((address_space(1))) void*)g,
            (__attribute__((address_space(3))) void*)(lds + elem),
            16, 0, 0);
    }
}

// swizzled LDS read offset: row, kb (element col, multiple of 8)
static __device__ __forceinline__ int sw_off(int row, int kb) {
    return row * 64 + (((kb >> 3) ^ (row & 7)) << 3);
}

// ---------------- stage 1: h = silu(x Wg^T) * (x Wu^T) -----------------
__global__ __launch_bounds__(256)
void k_gateup(const __hip_bfloat16* __restrict__ X,
              const __hip_bfloat16* __restrict__ Wg,
              const __hip_bfloat16* __restrict__ Wu,
              __hip_bfloat16* __restrict__ H)
{
    __shared__ __hip_bfloat16 sA[128 * 64];
    __shared__ __hip_bfloat16 sG[128 * 64];
    __shared__ __hip_bfloat16 sU[128 * 64];

    const int tid  = threadIdx.x;
    const int lane = tid & 63;
    const int wave = tid >> 6;
    const int wm = wave >> 1, wn = wave & 1;

    // grid reorder: per-XCD contiguous chunks (T1, 2752 = 8*344 exact),
    // then supertiles of 8 N-panels x 32 M-panels (m fastest -> consecutive
    // blocks share the same W panel; supertile WS ~48MB << L3).
    const int bid = blockIdx.x;
    const int o = (bid & 7) * 344 + (bid >> 3);
    int m, n;
    if (o < 2560) { int s = o >> 8, l = o & 255; n = s * 8 + (l >> 5); m = l & 31; }
    else          { int l = o - 2560;            n = 80 + (l >> 5);    m = l & 31; }
    const int m0 = m * 128;
    const int n0 = n * 128;
    const int r16 = lane & 15;
    const int g4  = lane >> 4;

    f32x4 accg[4][4], accu[4][4];
#pragma unroll
    for (int i = 0; i < 4; ++i)
#pragma unroll
        for (int j = 0; j < 4; ++j) {
            accg[i][j] = (f32x4){0.f, 0.f, 0.f, 0.f};
            accu[i][j] = (f32x4){0.f, 0.f, 0.f, 0.f};
        }

    const int nK = D_MODEL / 64;
    for (int t = 0; t < nK; ++t) {
        const int k0 = t * 64;
        stage_tile_sw(X  + (long)m0 * D_MODEL + k0, D_MODEL, sA, lane, wave);
        stage_tile_sw(Wg + (long)n0 * D_MODEL + k0, D_MODEL, sG, lane, wave);
        stage_tile_sw(Wu + (long)n0 * D_MODEL + k0, D_MODEL, sU, lane, wave);
        __syncthreads();
#pragma unroll
        for (int kk = 0; kk < 2; ++kk) {
            const int kb = kk * 32 + g4 * 8;
            short8 a[4], bg[4], bu[4];
#pragma unroll
            for (int i = 0; i < 4; ++i)
                a[i] = *reinterpret_cast<const short8*>(&sA[sw_off(wm * 64 + i * 16 + r16, kb)]);
#pragma unroll
            for (int j = 0; j < 4; ++j) {
                bg[j] = *reinterpret_cast<const short8*>(&sG[sw_off(wn * 64 + j * 16 + r16, kb)]);
                bu[j] = *reinterpret_cast<const short8*>(&sU[sw_off(wn * 64 + j * 16 + r16, kb)]);
            }
#pragma unroll
            for (int i = 0; i < 4; ++i)
#pragma unroll
                for (int j = 0; j < 4; ++j) {
                    accg[i][j] = __builtin_amdgcn_mfma_f32_16x16x32_bf16(a[i], bg[j], accg[i][j], 0, 0, 0);
                    accu[i][j] = __builtin_amdgcn_mfma_f32_16x16x32_bf16(a[i], bu[j], accu[i][j], 0, 0, 0);
                }
        }
        __syncthreads();
    }

    // epilogue: h = silu(g) * u, bf16 store
#pragma unroll
    for (int i = 0; i < 4; ++i)
#pragma unroll
        for (int j = 0; j < 4; ++j)
#pragma unroll
            for (int r = 0; r < 4; ++r) {
                int row = m0 + wm * 64 + i * 16 + g4 * 4 + r;
                int col = n0 + wn * 64 + j * 16 + r16;
                float g = accg[i][j][r];
                float u = accu[i][j][r];
                float s = g / (1.f + __expf(-g));
                H[(long)row * D_FF + col] = __float2bfloat16(s * u);
            }
}

// ---------------- stage 2: y = h Wd^T  (f32 output) --------------------
__global__ __launch_bounds__(256)
void k_down(const __hip_bfloat16* __restrict__ H,
            const __hip_bfloat16* __restrict__ Wd,
            float* __restrict__ Y)
{
    __shared__ __hip_bfloat16 sA[128 * 64];
    __shared__ __hip_bfloat16 sB[128 * 64];

    const int tid  = threadIdx.x;
    const int lane = tid & 63;
    const int wave = tid >> 6;
    const int wm = wave >> 1, wn = wave & 1;

    // 1024 blocks = 8 XCD chunks of 128; supertiles 8n x 32m, m fastest.
    const int bid = blockIdx.x;
    const int o = (bid & 7) * 128 + (bid >> 3);
    const int s = o >> 8, l = o & 255;
    const int n = s * 8 + (l >> 5);
    const int m = l & 31;
    const int m0 = m * 128;
    const int n0 = n * 128;
    const int r16 = lane & 15;
    const int g4  = lane >> 4;

    f32x4 acc[4][4];
#pragma unroll
    for (int i = 0; i < 4; ++i)
#pragma unroll
        for (int j = 0; j < 4; ++j)
            acc[i][j] = (f32x4){0.f, 0.f, 0.f, 0.f};

    const int nK = D_FF / 64;   // 172
    for (int t = 0; t < nK; ++t) {
        const int k0 = t * 64;
        stage_tile_sw(H  + (long)m0 * D_FF + k0, D_FF, sA, lane, wave);
        stage_tile_sw(Wd + (long)n0 * D_FF + k0, D_FF, sB, lane, wave);
        __syncthreads();
#pragma unroll
        for (int kk = 0; kk < 2; ++kk) {
            const int kb = kk * 32 + g4 * 8;
            short8 a[4], b[4];
#pragma unroll
            for (int i = 0; i < 4; ++i)
                a[i] = *reinterpret_cast<const short8*>(&sA[sw_off(wm * 64 + i * 16 + r16, kb)]);
#pragma unroll
            for (int j = 0; j < 4; ++j)
                b[j] = *reinterpret_cast<const short8*>(&sB[sw_off(wn * 64 + j * 16 + r16, kb)]);
#pragma unroll
            for (int i = 0; i < 4; ++i)
#pragma unroll
                for (int j = 0; j < 4; ++j)
                    acc[i][j] = __builtin_amdgcn_mfma_f32_16x16x32_bf16(a[i], b[j], acc[i][j], 0, 0, 0);
        }
        __syncthreads();
    }

#pragma unroll
    for (int i = 0; i < 4; ++i)
#pragma unroll
        for (int j = 0; j < 4; ++j)
#pragma unroll
            for (int r = 0; r < 4; ++r) {
                int row = m0 + wm * 64 + i * 16 + g4 * 4 + r;
                int col = n0 + wn * 64 + j * 16 + r16;
                Y[(long)row * D_MODEL + col] = acc[i][j][r];
            }
}

extern "C" void kernel_launch(void* const* d_in, const int* in_sizes, int n_in,
                              void* d_out, int out_size, void* d_ws, size_t ws_size,
                              hipStream_t stream) {
    const float* x  = (const float*)d_in[0];
    const float* wg = (const float*)d_in[1];
    const float* wu = (const float*)d_in[2];
    const float* wd = (const float*)d_in[3];
    float* y = (float*)d_out;

    char* ws = (char*)d_ws;
    const size_t szX  = (size_t)NTOK * D_MODEL * 2;
    const size_t szW  = (size_t)D_FF * D_MODEL * 2;
    __hip_bfloat16* Xb  = (__hip_bfloat16*)(ws);
    __hip_bfloat16* Wgb = (__hip_bfloat16*)(ws + szX);
    __hip_bfloat16* Wub = (__hip_bfloat16*)(ws + szX + szW);
    __hip_bfloat16* Wdb = (__hip_bfloat16*)(ws + szX + 2 * szW);
    __hip_bfloat16* Hb  = (__hip_bfloat16*)(ws + szX + 3 * szW);
    (void)ws_size; (void)out_size; (void)n_in; (void)in_sizes;

    const int nX = NTOK * D_MODEL / 8;
    const int nW = D_FF * D_MODEL / 8;
    k_cvt<<<(nX + 255) / 256, 256, 0, stream>>>(x, Xb, nX);
    k_cvt<<<(nW + 255) / 256, 256, 0, stream>>>(wg, Wgb, nW);
    k_cvt<<<(nW + 255) / 256, 256, 0, stream>>>(wu, Wub, nW);
    k_cvt<<<(nW + 255) / 256, 256, 0, stream>>>(wd, Wdb, nW);

    k_gateup<<<2752, 256, 0, stream>>>(Xb, Wgb, Wub, Hb);
    k_down<<<1024, 256, 0, stream>>>(Hb, Wdb, y);
}

// Round 3
// 1278.724 us; speedup vs baseline: 1.7364x; 1.7359x over previous
//
#include <hip/hip_runtime.h>
#include <hip/hip_bf16.h>

#define D_MODEL 4096
#define D_FF    11008
#define NTOK    4096   // 2*2048 tokens

typedef __attribute__((ext_vector_type(8))) short short8;
typedef __attribute__((ext_vector_type(4))) float f32x4;

// ---------------- fp32 -> bf16 convert (8 elems/thread) ----------------
__global__ void k_cvt(const float* __restrict__ in, __hip_bfloat16* __restrict__ out, int n8) {
    int i = blockIdx.x * blockDim.x + threadIdx.x;
    if (i >= n8) return;
    const float4* p = (const float4*)in;
    float4 v0 = p[(size_t)i * 2];
    float4 v1 = p[(size_t)i * 2 + 1];
    float vals[8] = {v0.x, v0.y, v0.z, v0.w, v1.x, v1.y, v1.z, v1.w};
    short8 o;
#pragma unroll
    for (int j = 0; j < 8; ++j) {
        __hip_bfloat16 b = __float2bfloat16(vals[j]);
        o[j] = *reinterpret_cast<short*>(&b);
    }
    *reinterpret_cast<short8*>(out + (size_t)i * 8) = o;
}

// ---- stage 1/4 of a 256x64 bf16 tile (1 gload_lds x 512 threads) ----
// LDS dest linear (wave-uniform base + lane*16B per HW); the swizzle is done
// by permuting the GLOBAL source chunk: phys chunk p of row r holds logical
// chunk p ^ (r&7). Read side applies the same XOR (rule #21).
static __device__ __forceinline__ void stage_q(
    const __hip_bfloat16* gbase, int ld, __hip_bfloat16* lds, int tid, int q)
{
    int ci = q * 512 + tid;            // 16B chunk index 0..2047
    int r  = ci >> 3;                  // row 0..255 (8 chunks of 8 bf16 per row)
    int p  = ci & 7;
    int c  = p ^ (r & 7);
    __builtin_amdgcn_global_load_lds(
        (const __attribute__((address_space(1))) void*)(gbase + (long)r * ld + c * 8),
        (__attribute__((address_space(3))) void*)(lds + (long)ci * 8),
        16, 0, 0);
}

// swizzled LDS read offset: row, kb = element col (multiple of 8)
static __device__ __forceinline__ int sw_off(int row, int kb) {
    return row * 64 + ((((kb >> 3) ^ (row & 7))) << 3);
}

// ---------------- 256x256 BK=64 double-buffered GEMM ----------------
// C[M][N] = A[M][K] * B[N][K]^T  (both inputs K-contiguous bf16)
// EPI 0: store silu(acc) as bf16      (gate proj)
// EPI 1: C *= acc in place (bf16)     (up proj; C holds silu(g))
// EPI 2: store acc as f32             (down proj)
template<int EPI>
__global__ __launch_bounds__(512, 2)
void k_gemm(const __hip_bfloat16* __restrict__ A,
            const __hip_bfloat16* __restrict__ B,
            void* __restrict__ C,
            const int M, const int N, const int K, const int nsw)
{
    extern __shared__ __hip_bfloat16 smem[];
    __hip_bfloat16* sA = smem;           // [2][256*64]
    __hip_bfloat16* sB = smem + 32768;   // [2][256*64]

    const int tid  = threadIdx.x;
    const int lane = tid & 63;
    const int wid  = tid >> 6;
    const int wm = wid >> 2, wn = wid & 3;   // 2 x 4 waves
    const int r16 = lane & 15, g4 = lane >> 4;

    // T1: bijective XCD chunks, then m-fastest (blocks sharing a B-panel
    // are consecutive; B-panel stays in L2, A stays in L3).
    const int bid = blockIdx.x;
    const int o = (bid & 7) * nsw + (bid >> 3);
    const int mt = M >> 8;
    const int n0 = (o / mt) << 8;
    const int m0 = (o % mt) << 8;

    const __hip_bfloat16* Abase = A + (long)m0 * K;
    const __hip_bfloat16* Bbase = B + (long)n0 * K;

    // prologue: stage tile 0 into buffer 0
#pragma unroll
    for (int q = 0; q < 4; ++q) {
        stage_q(Abase, K, sA, tid, q);
        stage_q(Bbase, K, sB, tid, q);
    }
    __syncthreads();

    f32x4 acc[8][4];
#pragma unroll
    for (int i = 0; i < 8; ++i)
#pragma unroll
        for (int j = 0; j < 4; ++j)
            acc[i][j] = (f32x4){0.f, 0.f, 0.f, 0.f};

    const int nk = K >> 6;
    for (int t = 0; t < nk; ++t) {
        const int a = t & 1;
        const __hip_bfloat16* cA = sA + a * 16384;
        const __hip_bfloat16* cB = sB + a * 16384;
        __hip_bfloat16* dA = sA + (a ^ 1) * 16384;
        __hip_bfloat16* dB = sB + (a ^ 1) * 16384;
        const __hip_bfloat16* nA = Abase + (t + 1) * 64;
        const __hip_bfloat16* nB = Bbase + (t + 1) * 64;
        const bool pf = (t + 1 < nk);

#pragma unroll
        for (int sp = 0; sp < 4; ++sp) {      // (iq, kk) = (sp>>1, sp&1)
            if (pf) {                         // issue prefetch FIRST
                stage_q(nA, K, dA, tid, sp);
                stage_q(nB, K, dB, tid, sp);
            }
            const int iq = sp >> 1, kk = sp & 1;
            short8 af[4], bf[4];
#pragma unroll
            for (int ii = 0; ii < 4; ++ii)
                af[ii] = *reinterpret_cast<const short8*>(
                    &cA[sw_off(wm * 128 + (iq * 4 + ii) * 16 + r16, kk * 32 + g4 * 8)]);
#pragma unroll
            for (int j = 0; j < 4; ++j)
                bf[j] = *reinterpret_cast<const short8*>(
                    &cB[sw_off(wn * 64 + j * 16 + r16, kk * 32 + g4 * 8)]);
#pragma unroll
            for (int ii = 0; ii < 4; ++ii)
#pragma unroll
                for (int j = 0; j < 4; ++j)
                    acc[iq * 4 + ii][j] = __builtin_amdgcn_mfma_f32_16x16x32_bf16(
                        af[ii], bf[j], acc[iq * 4 + ii][j], 0, 0, 0);
        }
        // single drain+barrier per K-tile; prefetch loads are ~4 sub-phases
        // old here so the compiler's vmcnt(0) is nearly free.
        __syncthreads();
    }

    float* Cf = (float*)C;
    __hip_bfloat16* Cb = (__hip_bfloat16*)C;
#pragma unroll
    for (int i = 0; i < 8; ++i)
#pragma unroll
        for (int j = 0; j < 4; ++j)
#pragma unroll
            for (int r = 0; r < 4; ++r) {
                long row = m0 + wm * 128 + i * 16 + g4 * 4 + r;
                long col = n0 + wn * 64 + j * 16 + r16;
                float v = acc[i][j][r];
                if (EPI == 0) {
                    float s = v / (1.f + __expf(-v));
                    Cb[row * N + col] = __float2bfloat16(s);
                } else if (EPI == 1) {
                    float gs = __bfloat162float(Cb[row * N + col]);
                    Cb[row * N + col] = __float2bfloat16(gs * v);
                } else {
                    Cf[row * N + col] = v;
                }
            }
}

extern "C" void kernel_launch(void* const* d_in, const int* in_sizes, int n_in,
                              void* d_out, int out_size, void* d_ws, size_t ws_size,
                              hipStream_t stream) {
    const float* x  = (const float*)d_in[0];
    const float* wg = (const float*)d_in[1];
    const float* wu = (const float*)d_in[2];
    const float* wd = (const float*)d_in[3];
    float* y = (float*)d_out;

    char* ws = (char*)d_ws;
    const size_t szX = (size_t)NTOK * D_MODEL * 2;
    const size_t szW = (size_t)D_FF * D_MODEL * 2;
    __hip_bfloat16* Xb  = (__hip_bfloat16*)(ws);
    __hip_bfloat16* Wgb = (__hip_bfloat16*)(ws + szX);
    __hip_bfloat16* Wub = (__hip_bfloat16*)(ws + szX + szW);
    __hip_bfloat16* Wdb = (__hip_bfloat16*)(ws + szX + 2 * szW);
    __hip_bfloat16* Hb  = (__hip_bfloat16*)(ws + szX + 3 * szW);
    (void)ws_size; (void)out_size; (void)n_in; (void)in_sizes;

    const size_t SMEM = 131072;  // 128 KiB dynamic LDS
    hipFuncSetAttribute((const void*)k_gemm<0>, hipFuncAttributeMaxDynamicSharedMemorySize, (int)SMEM);
    hipFuncSetAttribute((const void*)k_gemm<1>, hipFuncAttributeMaxDynamicSharedMemorySize, (int)SMEM);
    hipFuncSetAttribute((const void*)k_gemm<2>, hipFuncAttributeMaxDynamicSharedMemorySize, (int)SMEM);

    const int nX = NTOK * D_MODEL / 8;
    const int nW = D_FF * D_MODEL / 8;
    k_cvt<<<(nX + 255) / 256, 256, 0, stream>>>(x, Xb, nX);
    k_cvt<<<(nW + 255) / 256, 256, 0, stream>>>(wg, Wgb, nW);
    k_cvt<<<(nW + 255) / 256, 256, 0, stream>>>(wu, Wub, nW);
    k_cvt<<<(nW + 255) / 256, 256, 0, stream>>>(wd, Wdb, nW);

    // gate: Hb = silu(X Wg^T)
    k_gemm<0><<<688, 512, SMEM, stream>>>(Xb, Wgb, (void*)Hb, NTOK, D_FF, D_MODEL, 86);
    // up:   Hb *= X Wu^T   (in place)
    k_gemm<1><<<688, 512, SMEM, stream>>>(Xb, Wub, (void*)Hb, NTOK, D_FF, D_MODEL, 86);
    // down: Y = Hb Wd^T    (f32 out)
    k_gemm<2><<<256, 512, SMEM, stream>>>(Hb, Wdb, (void*)y, NTOK, D_MODEL, D_FF, 32);
}

// Round 4
// 1143.949 us; speedup vs baseline: 1.9410x; 1.1178x over previous
//
#include <hip/hip_runtime.h>
#include <hip/hip_bf16.h>

#define D_MODEL 4096
#define D_FF    11008
#define NTOK    4096   // 2*2048 tokens

typedef __attribute__((ext_vector_type(8))) short short8;
typedef __attribute__((ext_vector_type(4))) float f32x4;

// ---------------- fp32 -> bf16 convert (8 elems/thread) ----------------
__global__ void k_cvt(const float* __restrict__ in, __hip_bfloat16* __restrict__ out, int n8) {
    int i = blockIdx.x * blockDim.x + threadIdx.x;
    if (i >= n8) return;
    const float4* p = (const float4*)in;
    float4 v0 = p[(size_t)i * 2];
    float4 v1 = p[(size_t)i * 2 + 1];
    float vals[8] = {v0.x, v0.y, v0.z, v0.w, v1.x, v1.y, v1.z, v1.w};
    short8 o;
#pragma unroll
    for (int j = 0; j < 8; ++j) {
        __hip_bfloat16 b = __float2bfloat16(vals[j]);
        o[j] = *reinterpret_cast<short*>(&b);
    }
    *reinterpret_cast<short8*>(out + (size_t)i * 8) = o;
}

// ---- stage one 128x64 half-tile: 2 x global_load_lds per thread ----
// LDS dest linear; swizzle via permuted GLOBAL source chunk (rule #21):
// physical chunk p of row r holds logical chunk p ^ (r&7).
static __device__ __forceinline__ void stage_half(
    const __hip_bfloat16* g, int ld, __hip_bfloat16* lds, int tid)
{
#pragma unroll
    for (int s = 0; s < 2; ++s) {
        int ci = s * 512 + tid;            // 16B chunk 0..1023
        int r  = ci >> 3;                  // row 0..127
        int c  = (ci & 7) ^ (r & 7);       // logical chunk
        __builtin_amdgcn_global_load_lds(
            (const __attribute__((address_space(1))) void*)(g + (long)r * ld + c * 8),
            (__attribute__((address_space(3))) void*)(lds + ci * 8),
            16, 0, 0);
    }
}

// swizzled LDS read offset (row 0..255 within tile, kb = col, multiple of 8)
static __device__ __forceinline__ int sw_off(int row, int kb) {
    return row * 64 + ((((kb >> 3) ^ (row & 7))) << 3);
}

// One phase: {A-quadrant ds_reads (+all B at IQ==0) | stage 1 half-tile} ->
// barrier -> lgkmcnt(0) -> setprio(1) -> 16 MFMA -> setprio(0) -> barrier.
#define GEMM_PHASE(cA, cB, IQ, LOADB, STAGE, VMC)                              \
    {                                                                          \
        short8 af[2][2];                                                       \
        _Pragma("unroll")                                                      \
        for (int ii = 0; ii < 2; ++ii)                                         \
            _Pragma("unroll")                                                  \
            for (int kk = 0; kk < 2; ++kk)                                     \
                af[ii][kk] = *reinterpret_cast<const short8*>(                 \
                    &(cA)[sw_off(wm * 128 + ((IQ) * 2 + ii) * 16 + r16,        \
                                 kk * 32 + g4 * 8)]);                          \
        if (LOADB) {                                                           \
            _Pragma("unroll")                                                  \
            for (int kk = 0; kk < 2; ++kk)                                     \
                _Pragma("unroll")                                              \
                for (int j = 0; j < 4; ++j)                                    \
                    bfr[kk][j] = *reinterpret_cast<const short8*>(             \
                        &(cB)[sw_off(wn * 64 + j * 16 + r16,                   \
                                     kk * 32 + g4 * 8)]);                      \
        }                                                                      \
        STAGE;                                                                 \
        VMC;                                                                   \
        __builtin_amdgcn_s_barrier();                                          \
        asm volatile("s_waitcnt lgkmcnt(0)" ::: "memory");                     \
        __builtin_amdgcn_sched_barrier(0);                                     \
        __builtin_amdgcn_s_setprio(1);                                         \
        _Pragma("unroll")                                                      \
        for (int ii = 0; ii < 2; ++ii)                                         \
            _Pragma("unroll")                                                  \
            for (int j = 0; j < 4; ++j) {                                      \
                acc[(IQ) * 2 + ii][j] = __builtin_amdgcn_mfma_f32_16x16x32_bf16( \
                    af[ii][0], bfr[0][j], acc[(IQ) * 2 + ii][j], 0, 0, 0);     \
                acc[(IQ) * 2 + ii][j] = __builtin_amdgcn_mfma_f32_16x16x32_bf16( \
                    af[ii][1], bfr[1][j], acc[(IQ) * 2 + ii][j], 0, 0, 0);     \
            }                                                                  \
        __builtin_amdgcn_s_setprio(0);                                         \
        __builtin_amdgcn_sched_barrier(0);                                     \
        __builtin_amdgcn_s_barrier();                                          \
    }

#define VM4 do { if (pf) asm volatile("s_waitcnt vmcnt(4)" ::: "memory");      \
                 else    asm volatile("s_waitcnt vmcnt(0)" ::: "memory"); } while (0)
#define VMNONE do {} while (0)

// ---------------- 256x256 BK=64 8-phase GEMM ----------------
// C[M][N] = A[M][K] * B[N][K]^T (bf16, K-contiguous)
// EPI 0: store silu(acc) bf16 | EPI 1: C *= acc in place bf16 | EPI 2: f32
template<int EPI>
__global__ __launch_bounds__(512, 2)
void k_gemm(const __hip_bfloat16* __restrict__ A,
            const __hip_bfloat16* __restrict__ B,
            void* __restrict__ C,
            const int M, const int N, const int K, const int nsw)
{
    extern __shared__ __hip_bfloat16 smem[];
    __hip_bfloat16* sA = smem;           // [2 buf][256 rows][64]
    __hip_bfloat16* sB = smem + 32768;   // [2 buf][256 rows][64]

    const int tid  = threadIdx.x;
    const int lane = tid & 63;
    const int wid  = tid >> 6;
    const int wm = wid >> 2, wn = wid & 3;   // 2 x 4 waves
    const int r16 = lane & 15, g4 = lane >> 4;

    // T1: bijective XCD chunks, m-fastest inside chunk
    const int bid = blockIdx.x;
    const int o = (bid & 7) * nsw + (bid >> 3);
    const int mt = M >> 8;
    const int n0 = (o / mt) << 8;
    const int m0 = (o % mt) << 8;

    const __hip_bfloat16* Ab = A + (long)m0 * K;
    const __hip_bfloat16* Bb = B + (long)n0 * K;
    const long h1 = (long)128 * K;   // global offset of rows 128..255

    // prologue: K-tile 0 (4 halves) then B of K-tile 1 (2 halves)
    stage_half(Ab,            K, sA + 0,             tid);
    stage_half(Ab + h1,       K, sA + 8192,          tid);
    stage_half(Bb,            K, sB + 0,             tid);
    stage_half(Bb + h1,       K, sB + 8192,          tid);
    stage_half(Bb + 64,       K, sB + 16384,         tid);
    stage_half(Bb + h1 + 64,  K, sB + 16384 + 8192,  tid);
    asm volatile("s_waitcnt vmcnt(4)" ::: "memory");   // K-tile0 landed
    __builtin_amdgcn_s_barrier();

    f32x4 acc[8][4];
#pragma unroll
    for (int i = 0; i < 8; ++i)
#pragma unroll
        for (int j = 0; j < 4; ++j)
            acc[i][j] = (f32x4){0.f, 0.f, 0.f, 0.f};

    const int nk = K >> 6;        // even (64 or 172)
    const int niter = nk >> 1;

    for (int it = 0; it < niter; ++it) {
        const bool pf = (it + 1 < niter);
        const long ko  = (long)(2 * it + 1) * 64;   // odd K-tile col
        const long kn2 = (long)(2 * it + 2) * 64;   // next even
        const long kn3 = (long)(2 * it + 3) * 64;   // next odd

        // ---- phases 1-4: K-tile 2it from buf0 ----
        {
            const __hip_bfloat16* cA = sA;
            const __hip_bfloat16* cB = sB;
            short8 bfr[2][4];
            GEMM_PHASE(cA, cB, 0, 1,
                stage_half(Ab + ko,      K, sA + 16384,        tid), VMNONE);
            GEMM_PHASE(cA, cB, 1, 0,
                stage_half(Ab + h1 + ko, K, sA + 16384 + 8192, tid), VMNONE);
            GEMM_PHASE(cA, cB, 2, 0,
                if (pf) stage_half(Bb + kn2,      K, sB + 0,    tid), VMNONE);
            GEMM_PHASE(cA, cB, 3, 0,
                if (pf) stage_half(Bb + h1 + kn2, K, sB + 8192, tid), VM4);
        }
        // ---- phases 5-8: K-tile 2it+1 from buf1 ----
        {
            const __hip_bfloat16* cA = sA + 16384;
            const __hip_bfloat16* cB = sB + 16384;
            short8 bfr[2][4];
            GEMM_PHASE(cA, cB, 0, 1,
                if (pf) stage_half(Ab + kn2,      K, sA + 0,    tid), VMNONE);
            GEMM_PHASE(cA, cB, 1, 0,
                if (pf) stage_half(Ab + h1 + kn2, K, sA + 8192, tid), VMNONE);
            GEMM_PHASE(cA, cB, 2, 0,
                if (pf) stage_half(Bb + kn3,      K, sB + 16384, tid), VMNONE);
            GEMM_PHASE(cA, cB, 3, 0,
                if (pf) stage_half(Bb + h1 + kn3, K, sB + 16384 + 8192, tid), VM4);
        }
    }

    float* Cf = (float*)C;
    __hip_bfloat16* Cb = (__hip_bfloat16*)C;
#pragma unroll
    for (int i = 0; i < 8; ++i)
#pragma unroll
        for (int j = 0; j < 4; ++j)
#pragma unroll
            for (int r = 0; r < 4; ++r) {
                long row = m0 + wm * 128 + i * 16 + g4 * 4 + r;
                long col = n0 + wn * 64 + j * 16 + r16;
                float v = acc[i][j][r];
                if (EPI == 0) {
                    float s = v / (1.f + __expf(-v));
                    Cb[row * N + col] = __float2bfloat16(s);
                } else if (EPI == 1) {
                    float gs = __bfloat162float(Cb[row * N + col]);
                    Cb[row * N + col] = __float2bfloat16(gs * v);
                } else {
                    Cf[row * N + col] = v;
                }
            }
}

extern "C" void kernel_launch(void* const* d_in, const int* in_sizes, int n_in,
                              void* d_out, int out_size, void* d_ws, size_t ws_size,
                              hipStream_t stream) {
    const float* x  = (const float*)d_in[0];
    const float* wg = (const float*)d_in[1];
    const float* wu = (const float*)d_in[2];
    const float* wd = (const float*)d_in[3];
    float* y = (float*)d_out;

    char* ws = (char*)d_ws;
    const size_t szX = (size_t)NTOK * D_MODEL * 2;
    const size_t szW = (size_t)D_FF * D_MODEL * 2;
    __hip_bfloat16* Xb  = (__hip_bfloat16*)(ws);
    __hip_bfloat16* Wgb = (__hip_bfloat16*)(ws + szX);
    __hip_bfloat16* Wub = (__hip_bfloat16*)(ws + szX + szW);
    __hip_bfloat16* Wdb = (__hip_bfloat16*)(ws + szX + 2 * szW);
    __hip_bfloat16* Hb  = (__hip_bfloat16*)(ws + szX + 3 * szW);
    (void)ws_size; (void)out_size; (void)n_in; (void)in_sizes;

    const size_t SMEM = 131072;  // 128 KiB dynamic LDS
    hipFuncSetAttribute((const void*)k_gemm<0>, hipFuncAttributeMaxDynamicSharedMemorySize, (int)SMEM);
    hipFuncSetAttribute((const void*)k_gemm<1>, hipFuncAttributeMaxDynamicSharedMemorySize, (int)SMEM);
    hipFuncSetAttribute((const void*)k_gemm<2>, hipFuncAttributeMaxDynamicSharedMemorySize, (int)SMEM);

    const int nX = NTOK * D_MODEL / 8;
    const int nW = D_FF * D_MODEL / 8;
    k_cvt<<<(nX + 255) / 256, 256, 0, stream>>>(x, Xb, nX);
    k_cvt<<<(nW + 255) / 256, 256, 0, stream>>>(wg, Wgb, nW);
    k_cvt<<<(nW + 255) / 256, 256, 0, stream>>>(wu, Wub, nW);
    k_cvt<<<(nW + 255) / 256, 256, 0, stream>>>(wd, Wdb, nW);

    // gate: Hb = silu(X Wg^T)
    k_gemm<0><<<688, 512, SMEM, stream>>>(Xb, Wgb, (void*)Hb, NTOK, D_FF, D_MODEL, 86);
    // up:   Hb *= X Wu^T   (in place)
    k_gemm<1><<<688, 512, SMEM, stream>>>(Xb, Wub, (void*)Hb, NTOK, D_FF, D_MODEL, 86);
    // down: Y = Hb Wd^T    (f32 out)
    k_gemm<2><<<256, 512, SMEM, stream>>>(Hb, Wdb, (void*)y, NTOK, D_MODEL, D_FF, 32);
}

// Round 5
// 1067.825 us; speedup vs baseline: 2.0794x; 1.0713x over previous
//
#include <hip/hip_runtime.h>
#include <hip/hip_bf16.h>

#define D_MODEL 4096
#define D_FF    11008
#define NTOK    4096   // 2*2048 tokens

typedef __attribute__((ext_vector_type(8))) short short8;
typedef __attribute__((ext_vector_type(4))) float f32x4;

// ---------------- fp32 -> bf16 convert (8 elems/thread) ----------------
__global__ void k_cvt(const float* __restrict__ in, __hip_bfloat16* __restrict__ out, int n8) {
    int i = blockIdx.x * blockDim.x + threadIdx.x;
    if (i >= n8) return;
    const float4* p = (const float4*)in;
    float4 v0 = p[(size_t)i * 2];
    float4 v1 = p[(size_t)i * 2 + 1];
    float vals[8] = {v0.x, v0.y, v0.z, v0.w, v1.x, v1.y, v1.z, v1.w};
    short8 o;
#pragma unroll
    for (int j = 0; j < 8; ++j) {
        __hip_bfloat16 b = __float2bfloat16(vals[j]);
        o[j] = *reinterpret_cast<short*>(&b);
    }
    *reinterpret_cast<short8*>(out + (size_t)i * 8) = o;
}

// ---- stage one 128x64 half-tile: 2 x global_load_lds per thread (512t) ----
// LDS dest linear; swizzle via permuted GLOBAL source chunk (rule #21):
// physical chunk p of row r holds logical chunk p ^ (r&7).
static __device__ __forceinline__ void stage_half(
    const __hip_bfloat16* g, int ld, __hip_bfloat16* lds, int tid)
{
#pragma unroll
    for (int s = 0; s < 2; ++s) {
        int ci = s * 512 + tid;            // 16B chunk 0..1023
        int r  = ci >> 3;                  // row 0..127
        int c  = (ci & 7) ^ (r & 7);       // logical chunk
        __builtin_amdgcn_global_load_lds(
            (const __attribute__((address_space(1))) void*)(g + (long)r * ld + c * 8),
            (__attribute__((address_space(3))) void*)(lds + ci * 8),
            16, 0, 0);
    }
}

// swizzled LDS read offset (row within tile-half, kb = col, multiple of 8)
static __device__ __forceinline__ int sw_off(int row, int kb) {
    return row * 64 + ((((kb >> 3) ^ (row & 7))) << 3);
}

// ================= fused gate+up kernel: H = silu(X Wg^T) * (X Wu^T) ======
// tile 256M x 128N, BK=64, 8 waves (2M x 4N), per-wave out 128x32 per matrix.
// LDS: A dbuf 2x32KB + B ring 3x32KB (G half + U half) = 160 KiB exactly.
// B staged 2 K-tiles ahead (6-7 phases) to cover HBM latency.

#define FPHASE(IQ, LOADB, STAGE, VMC)                                          \
    {                                                                          \
        short8 af[2][2];                                                       \
        _Pragma("unroll")                                                      \
        for (int ii = 0; ii < 2; ++ii)                                         \
            _Pragma("unroll")                                                  \
            for (int kk = 0; kk < 2; ++kk)                                     \
                af[ii][kk] = *reinterpret_cast<const short8*>(                 \
                    &cA[sw_off(wm * 128 + ((IQ) * 2 + ii) * 16 + r16,          \
                               kk * 32 + g4 * 8)]);                            \
        if (LOADB) {                                                           \
            _Pragma("unroll")                                                  \
            for (int kk = 0; kk < 2; ++kk)                                     \
                _Pragma("unroll")                                              \
                for (int j = 0; j < 2; ++j) {                                  \
                    bg[kk][j] = *reinterpret_cast<const short8*>(              \
                        &cB[sw_off(wn * 32 + j * 16 + r16, kk * 32 + g4 * 8)]); \
                    bu[kk][j] = *reinterpret_cast<const short8*>(              \
                        &cB[8192 + sw_off(wn * 32 + j * 16 + r16, kk * 32 + g4 * 8)]); \
                }                                                              \
        }                                                                      \
        STAGE;                                                                 \
        VMC;                                                                   \
        if (LOADB) asm volatile("s_waitcnt lgkmcnt(8)" ::: "memory");          \
        __builtin_amdgcn_s_barrier();                                          \
        asm volatile("s_waitcnt lgkmcnt(0)" ::: "memory");                     \
        __builtin_amdgcn_sched_barrier(0);                                     \
        __builtin_amdgcn_s_setprio(1);                                         \
        _Pragma("unroll")                                                      \
        for (int ii = 0; ii < 2; ++ii)                                         \
            _Pragma("unroll")                                                  \
            for (int j = 0; j < 2; ++j) {                                      \
                accg[(IQ) * 2 + ii][j] = __builtin_amdgcn_mfma_f32_16x16x32_bf16( \
                    af[ii][0], bg[0][j], accg[(IQ) * 2 + ii][j], 0, 0, 0);     \
                accg[(IQ) * 2 + ii][j] = __builtin_amdgcn_mfma_f32_16x16x32_bf16( \
                    af[ii][1], bg[1][j], accg[(IQ) * 2 + ii][j], 0, 0, 0);     \
                accu[(IQ) * 2 + ii][j] = __builtin_amdgcn_mfma_f32_16x16x32_bf16( \
                    af[ii][0], bu[0][j], accu[(IQ) * 2 + ii][j], 0, 0, 0);     \
                accu[(IQ) * 2 + ii][j] = __builtin_amdgcn_mfma_f32_16x16x32_bf16( \
                    af[ii][1], bu[1][j], accu[(IQ) * 2 + ii][j], 0, 0, 0);     \
            }                                                                  \
        __builtin_amdgcn_s_setprio(0);                                         \
        __builtin_amdgcn_sched_barrier(0);                                     \
        __builtin_amdgcn_s_barrier();                                          \
    }

__global__ __launch_bounds__(512, 2)
void k_gateup(const __hip_bfloat16* __restrict__ X,
              const __hip_bfloat16* __restrict__ Wg,
              const __hip_bfloat16* __restrict__ Wu,
              __hip_bfloat16* __restrict__ H)
{
    extern __shared__ __hip_bfloat16 smem[];
    __hip_bfloat16* sA = smem;           // 2 bufs x 16384 elems (256x64)
    __hip_bfloat16* sB = smem + 32768;   // 3 ring slots x 16384 (G 128x64 | U 128x64)

    const int tid  = threadIdx.x;
    const int lane = tid & 63;
    const int wid  = tid >> 6;
    const int wm = wid >> 2, wn = wid & 3;   // 2M x 4N waves
    const int r16 = lane & 15, g4 = lane >> 4;

    // T1: bijective XCD chunks (1376 = 8*172), m-fastest inside chunk
    const int bid = blockIdx.x;
    const int o = (bid & 7) * 172 + (bid >> 3);
    const int n0 = (o >> 4) * 128;       // 86 n-panels of 128
    const int m0 = (o & 15) * 256;       // 16 m-panels of 256

    const int K = D_MODEL;
    const __hip_bfloat16* Ab = X  + (long)m0 * K;
    const __hip_bfloat16* Gb = Wg + (long)n0 * K;
    const __hip_bfloat16* Ub = Wu + (long)n0 * K;
    const long h1 = (long)128 * K;

    // prologue: A0 (2 halves), B0 (G+U), B1 (G+U)
    stage_half(Ab,           K, sA + 0,              tid);
    stage_half(Ab + h1,      K, sA + 8192,           tid);
    stage_half(Gb,           K, sB + 0,              tid);
    stage_half(Ub,           K, sB + 8192,           tid);
    stage_half(Gb + 64,      K, sB + 16384,          tid);
    stage_half(Ub + 64,      K, sB + 16384 + 8192,   tid);
    asm volatile("s_waitcnt vmcnt(4)" ::: "memory");   // A0+B0 landed, B1 flying
    __builtin_amdgcn_s_barrier();

    f32x4 accg[8][2], accu[8][2];
#pragma unroll
    for (int i = 0; i < 8; ++i)
#pragma unroll
        for (int j = 0; j < 2; ++j) {
            accg[i][j] = (f32x4){0.f, 0.f, 0.f, 0.f};
            accu[i][j] = (f32x4){0.f, 0.f, 0.f, 0.f};
        }

    const int nk = K >> 6;   // 64 K-tiles
    int rb = 0;              // B ring read slot; write slot = (rb+2)%3
    for (int t = 0; t < nk; ++t) {
        const __hip_bfloat16* cA = sA + (t & 1) * 16384;
        const __hip_bfloat16* cB = sB + rb * 16384;
        __hip_bfloat16* nA = sA + ((t & 1) ^ 1) * 16384;
        int wb = rb + 2; if (wb >= 3) wb -= 3;
        __hip_bfloat16* wB = sB + wb * 16384;
        const bool pf1 = (t + 1 < nk);
        const bool pf2 = (t + 2 < nk);
        const long kc1 = (long)(t + 1) * 64;
        const long kc2 = (long)(t + 2) * 64;
        short8 bg[2][2], bu[2][2];

        FPHASE(0, 1, if (pf1) stage_half(Ab + kc1,      K, nA,        tid), );
        FPHASE(1, 0, if (pf1) stage_half(Ab + h1 + kc1, K, nA + 8192, tid), );
        FPHASE(2, 0, if (pf2) stage_half(Gb + kc2,      K, wB,        tid), );
        FPHASE(3, 0, if (pf2) stage_half(Ub + kc2,      K, wB + 8192, tid),
               do { if (pf2) asm volatile("s_waitcnt vmcnt(4)" ::: "memory");
                    else     asm volatile("s_waitcnt vmcnt(0)" ::: "memory"); } while (0));

        rb = rb + 1; if (rb >= 3) rb -= 3;
    }

    // epilogue: h = silu(g) * u
#pragma unroll
    for (int i = 0; i < 8; ++i)
#pragma unroll
        for (int j = 0; j < 2; ++j)
#pragma unroll
            for (int r = 0; r < 4; ++r) {
                long row = m0 + wm * 128 + i * 16 + g4 * 4 + r;
                long col = n0 + wn * 32 + j * 16 + r16;
                float g = accg[i][j][r];
                float u = accu[i][j][r];
                float s = g / (1.f + __expf(-g));
                H[row * D_FF + col] = __float2bfloat16(s * u);
            }
}

// ================= down proj: Y = H Wd^T (f32 out), 8-phase 2-tile ========
#define DPHASE(cA, cB, IQ, LOADB, STAGE, VMC)                                  \
    {                                                                          \
        short8 af[2][2];                                                       \
        _Pragma("unroll")                                                      \
        for (int ii = 0; ii < 2; ++ii)                                         \
            _Pragma("unroll")                                                  \
            for (int kk = 0; kk < 2; ++kk)                                     \
                af[ii][kk] = *reinterpret_cast<const short8*>(                 \
                    &(cA)[sw_off(wm * 128 + ((IQ) * 2 + ii) * 16 + r16,        \
                                 kk * 32 + g4 * 8)]);                          \
        if (LOADB) {                                                           \
            _Pragma("unroll")                                                  \
            for (int kk = 0; kk < 2; ++kk)                                     \
                _Pragma("unroll")                                              \
                for (int j = 0; j < 4; ++j)                                    \
                    bfr[kk][j] = *reinterpret_cast<const short8*>(             \
                        &(cB)[sw_off(wn * 64 + j * 16 + r16,                   \
                                     kk * 32 + g4 * 8)]);                      \
        }                                                                      \
        STAGE;                                                                 \
        VMC;                                                                   \
        if (LOADB) asm volatile("s_waitcnt lgkmcnt(8)" ::: "memory");          \
        __builtin_amdgcn_s_barrier();                                          \
        asm volatile("s_waitcnt lgkmcnt(0)" ::: "memory");                     \
        __builtin_amdgcn_sched_barrier(0);                                     \
        __builtin_amdgcn_s_setprio(1);                                         \
        _Pragma("unroll")                                                      \
        for (int ii = 0; ii < 2; ++ii)                                         \
            _Pragma("unroll")                                                  \
            for (int j = 0; j < 4; ++j) {                                      \
                acc[(IQ) * 2 + ii][j] = __builtin_amdgcn_mfma_f32_16x16x32_bf16( \
                    af[ii][0], bfr[0][j], acc[(IQ) * 2 + ii][j], 0, 0, 0);     \
                acc[(IQ) * 2 + ii][j] = __builtin_amdgcn_mfma_f32_16x16x32_bf16( \
                    af[ii][1], bfr[1][j], acc[(IQ) * 2 + ii][j], 0, 0, 0);     \
            }                                                                  \
        __builtin_amdgcn_s_setprio(0);                                         \
        __builtin_amdgcn_sched_barrier(0);                                     \
        __builtin_amdgcn_s_barrier();                                          \
    }

#define VM4D do { if (pf) asm volatile("s_waitcnt vmcnt(4)" ::: "memory");     \
                  else    asm volatile("s_waitcnt vmcnt(0)" ::: "memory"); } while (0)

__global__ __launch_bounds__(512, 2)
void k_down(const __hip_bfloat16* __restrict__ A,
            const __hip_bfloat16* __restrict__ B,
            float* __restrict__ Y)
{
    extern __shared__ __hip_bfloat16 smem[];
    __hip_bfloat16* sA = smem;           // [2 buf][256][64]
    __hip_bfloat16* sB = smem + 32768;

    const int tid  = threadIdx.x;
    const int lane = tid & 63;
    const int wid  = tid >> 6;
    const int wm = wid >> 2, wn = wid & 3;
    const int r16 = lane & 15, g4 = lane >> 4;

    const int bid = blockIdx.x;          // 256 = 8*32
    const int o = (bid & 7) * 32 + (bid >> 3);
    const int n0 = (o >> 4) << 8;
    const int m0 = (o & 15) << 8;

    const int K = D_FF;
    const int N = D_MODEL;
    const __hip_bfloat16* Ab = A + (long)m0 * K;
    const __hip_bfloat16* Bb = B + (long)n0 * K;
    const long h1 = (long)128 * K;

    stage_half(Ab,            K, sA + 0,             tid);
    stage_half(Ab + h1,       K, sA + 8192,          tid);
    stage_half(Bb,            K, sB + 0,             tid);
    stage_half(Bb + h1,       K, sB + 8192,          tid);
    stage_half(Bb + 64,       K, sB + 16384,         tid);
    stage_half(Bb + h1 + 64,  K, sB + 16384 + 8192,  tid);
    asm volatile("s_waitcnt vmcnt(4)" ::: "memory");
    __builtin_amdgcn_s_barrier();

    f32x4 acc[8][4];
#pragma unroll
    for (int i = 0; i < 8; ++i)
#pragma unroll
        for (int j = 0; j < 4; ++j)
            acc[i][j] = (f32x4){0.f, 0.f, 0.f, 0.f};

    const int nk = K >> 6;        // 172
    const int niter = nk >> 1;    // 86

    for (int it = 0; it < niter; ++it) {
        const bool pf = (it + 1 < niter);
        const long ko  = (long)(2 * it + 1) * 64;
        const long kn2 = (long)(2 * it + 2) * 64;
        const long kn3 = (long)(2 * it + 3) * 64;
        {
            const __hip_bfloat16* cA = sA;
            const __hip_bfloat16* cB = sB;
            short8 bfr[2][4];
            DPHASE(cA, cB, 0, 1,
                stage_half(Ab + ko,      K, sA + 16384,        tid), );
            DPHASE(cA, cB, 1, 0,
                stage_half(Ab + h1 + ko, K, sA + 16384 + 8192, tid), );
            DPHASE(cA, cB, 2, 0,
                if (pf) stage_half(Bb + kn2,      K, sB + 0,    tid), );
            DPHASE(cA, cB, 3, 0,
                if (pf) stage_half(Bb + h1 + kn2, K, sB + 8192, tid), VM4D);
        }
        {
            const __hip_bfloat16* cA = sA + 16384;
            const __hip_bfloat16* cB = sB + 16384;
            short8 bfr[2][4];
            DPHASE(cA, cB, 0, 1,
                if (pf) stage_half(Ab + kn2,      K, sA + 0,    tid), );
            DPHASE(cA, cB, 1, 0,
                if (pf) stage_half(Ab + h1 + kn2, K, sA + 8192, tid), );
            DPHASE(cA, cB, 2, 0,
                if (pf) stage_half(Bb + kn3,      K, sB + 16384, tid), );
            DPHASE(cA, cB, 3, 0,
                if (pf) stage_half(Bb + h1 + kn3, K, sB + 16384 + 8192, tid), VM4D);
        }
    }

#pragma unroll
    for (int i = 0; i < 8; ++i)
#pragma unroll
        for (int j = 0; j < 4; ++j)
#pragma unroll
            for (int r = 0; r < 4; ++r) {
                long row = m0 + wm * 128 + i * 16 + g4 * 4 + r;
                long col = n0 + wn * 64 + j * 16 + r16;
                Y[row * N + col] = acc[i][j][r];
            }
}

extern "C" void kernel_launch(void* const* d_in, const int* in_sizes, int n_in,
                              void* d_out, int out_size, void* d_ws, size_t ws_size,
                              hipStream_t stream) {
    const float* x  = (const float*)d_in[0];
    const float* wg = (const float*)d_in[1];
    const float* wu = (const float*)d_in[2];
    const float* wd = (const float*)d_in[3];
    float* y = (float*)d_out;

    char* ws = (char*)d_ws;
    const size_t szX = (size_t)NTOK * D_MODEL * 2;
    const size_t szW = (size_t)D_FF * D_MODEL * 2;
    __hip_bfloat16* Xb  = (__hip_bfloat16*)(ws);
    __hip_bfloat16* Wgb = (__hip_bfloat16*)(ws + szX);
    __hip_bfloat16* Wub = (__hip_bfloat16*)(ws + szX + szW);
    __hip_bfloat16* Wdb = (__hip_bfloat16*)(ws + szX + 2 * szW);
    __hip_bfloat16* Hb  = (__hip_bfloat16*)(ws + szX + 3 * szW);
    (void)ws_size; (void)out_size; (void)n_in; (void)in_sizes;

    const int SMEM_GU = 163840;  // 160 KiB: A 2x32KB + B ring 3x32KB
    const int SMEM_D  = 131072;  // 128 KiB
    hipFuncSetAttribute((const void*)k_gateup, hipFuncAttributeMaxDynamicSharedMemorySize, SMEM_GU);
    hipFuncSetAttribute((const void*)k_down,   hipFuncAttributeMaxDynamicSharedMemorySize, SMEM_D);

    const int nX = NTOK * D_MODEL / 8;
    const int nW = D_FF * D_MODEL / 8;
    k_cvt<<<(nX + 255) / 256, 256, 0, stream>>>(x, Xb, nX);
    k_cvt<<<(nW + 255) / 256, 256, 0, stream>>>(wg, Wgb, nW);
    k_cvt<<<(nW + 255) / 256, 256, 0, stream>>>(wu, Wub, nW);
    k_cvt<<<(nW + 255) / 256, 256, 0, stream>>>(wd, Wdb, nW);

    // fused: Hb = silu(X Wg^T) * (X Wu^T)
    k_gateup<<<1376, 512, SMEM_GU, stream>>>(Xb, Wgb, Wub, Hb);
    // down:  Y = Hb Wd^T (f32 out)
    k_down<<<256, 512, SMEM_D, stream>>>(Hb, Wdb, y);
}